// Round 6
// baseline (377.183 us; speedup 1.0000x reference)
//
#include <hip/hip_runtime.h>

// ---------------------------------------------------------------------------
// ElementwiseTensorProducts — wave-autonomous, transpose-free bf16-MFMA kernel.
// Grid 4096 x 64 thr (1 wave), zero barriers, 6 KB LDS.
//
// Trick: proj MFMAs run with SWAPPED operands (A = W rows = ranks, B = z rows
// = tokens), so proj C-layout = (lane = token, regs = ranks). With the
// k-interleaved output-weight layout (kk even/odd = pair), the out-GEMM
// A-fragments for the paired K-regions are the SAME lane's product values —
// no transpose, pure register packing. Only q111 (kk>=128, unpaired) crosses
// lg-groups -> tiny 3 x 2 KB swizzled LDS staging.
// Products fused per rank-tile mt (cross products never mix ranks), so acc
// chunks die early and MFMA overlaps product VALU.
// ---------------------------------------------------------------------------

typedef float  f32x4  __attribute__((ext_vector_type(4)));
typedef __bf16 bf16x8 __attribute__((ext_vector_type(8)));

#define LDS_BYTES 6144

// fragment catalog in d_ws: wsf[fid*64 + lane], 16 B each (UNCHANGED vs R5)
// FA: proj weights  (mat:4)(mt:4)(k:4)                ids [0,64)
// FB0: W0o' k-interleaved p00/p110   (n8:8)(k:4)      ids [64,96)
// FB1: W1o' k-interleaved q011/q101 | q111 (n8:8)(k6:6) ids [96,144)
#define FA_ID(mat,n,k) (((mat)*4+(n))*4+(k))
#define FB0_ID(n8,k)   (64 + (n8)*4 + (k))
#define FB1_ID(n8,k6)  (96 + (n8)*6 + (k6))
#define NFRAG 144
#define WS_NEED (NFRAG * 64 * 16)

__device__ __forceinline__ unsigned packbf(float lo, float hi) {
    unsigned a = (unsigned)__builtin_bit_cast(unsigned short, (__bf16)lo);
    unsigned b = (unsigned)__builtin_bit_cast(unsigned short, (__bf16)hi);
    return a | (b << 16);
}
__device__ __forceinline__ bf16x8 cvtW(const float* p) {
    float4 a = *(const float4*)p;
    float4 b = *(const float4*)(p + 4);
    bf16x8 r;
    r[0] = (__bf16)a.x; r[1] = (__bf16)a.y; r[2] = (__bf16)a.z; r[3] = (__bf16)a.w;
    r[4] = (__bf16)b.x; r[5] = (__bf16)b.y; r[6] = (__bf16)b.z; r[7] = (__bf16)b.w;
    return r;
}
__device__ __forceinline__ f32x4 mm(bf16x8 a, bf16x8 b, f32x4 c) {
    return __builtin_amdgcn_mfma_f32_16x16x32_bf16(a, b, c, 0, 0, 0);
}
// interleave (a0,b0,a1,b1,a2,b2,a3,b3)
__device__ __forceinline__ bf16x8 pack8(f32x4 a, f32x4 b) {
    bf16x8 r;
    #pragma unroll
    for (int j = 0; j < 4; ++j) { r[2 * j] = (__bf16)a[j]; r[2 * j + 1] = (__bf16)b[j]; }
    return r;
}

// k-interleave maps (setup + fallback):
__device__ __forceinline__ int map_b0(int kk) { return (kk & 1) ? 64 + (kk >> 1) : (kk >> 1); }
__device__ __forceinline__ int map_b1(int kk) { return kk >= 128 ? kk : ((kk & 1) ? 64 + (kk >> 1) : (kk >> 1)); }

__device__ __forceinline__ bf16x8 gatherB0(const float* W0o, int n8, int k, int lr, int lg) {
    bf16x8 r; const int c = n8 * 16 + lr;
    #pragma unroll
    for (int e = 0; e < 8; ++e) r[e] = (__bf16)W0o[c * 128 + map_b0(k * 32 + lg * 8 + e)];
    return r;
}
__device__ __forceinline__ bf16x8 gatherB1(const float* W1o, int n8, int k6, int lr, int lg) {
    bf16x8 r; const int c = n8 * 16 + lr;
    #pragma unroll
    for (int e = 0; e < 8; ++e) r[e] = (__bf16)W1o[c * 192 + map_b1(k6 * 32 + lg * 8 + e)];
    return r;
}

// ---------------- setup: fp32 weights -> bf16 fragment buffer (unchanged) ---
__global__ void etp_setup(const float* __restrict__ W0l, const float* __restrict__ W0r,
                          const float* __restrict__ W1l, const float* __restrict__ W1r,
                          const float* __restrict__ W0o, const float* __restrict__ W1o,
                          bf16x8* __restrict__ wsf)
{
    const int gid = blockIdx.x * 256 + threadIdx.x;
    if (gid >= NFRAG * 64) return;
    const int fid = gid >> 6, l = gid & 63, lr = l & 15, lg = l >> 4;
    bf16x8 r;
    if (fid < 64) {
        const int mat = fid >> 4, n = (fid >> 2) & 3, k = fid & 3;
        const float* Wm = (mat == 0) ? W0l : (mat == 1) ? W0r : (mat == 2) ? W1l : W1r;
        r = cvtW(Wm + (n * 16 + lr) * 128 + k * 32 + lg * 8);
    } else if (fid < 96) {
        const int f = fid - 64;
        r = gatherB0(W0o, f >> 2, f & 3, lr, lg);
    } else {
        const int f = fid - 96;
        r = gatherB1(W1o, f / 6, f % 6, lr, lg);
    }
    wsf[fid * 64 + l] = r;
}

// ---------------- main kernel ------------------------------------------------
template <bool WS>
__global__ __launch_bounds__(64, 4)
void etp_main(const float* __restrict__ z0, const float* __restrict__ z1,
              const float* __restrict__ W0l, const float* __restrict__ b0l,
              const float* __restrict__ W0r, const float* __restrict__ b0r,
              const float* __restrict__ W1l, const float* __restrict__ W1r,
              const float* __restrict__ W0o, const float* __restrict__ b0o,
              const float* __restrict__ W1o,
              const bf16x8* __restrict__ wsf,
              float* __restrict__ out0, float* __restrict__ out1)
{
    __shared__ __align__(16) unsigned char smem[LDS_BYTES];   // 3 x 2KB q111 bufs
    const int l  = threadIdx.x;
    const int lr = l & 15;     // token (B n-row, proj-C col, out-A row, out-C col idx)
    const int lg = l >> 4;
    const int m0 = blockIdx.x * 16;

    // ---- z B-fragments (rows = tokens), fp32 -> bf16, read-once ------------
    bf16x8 zb0[4], zb1[3][4];
    #pragma unroll
    for (int k = 0; k < 4; ++k)
        zb0[k] = cvtW(z0 + (size_t)(m0 + lr) * 128 + k * 32 + lg * 8);
    #pragma unroll
    for (int i = 0; i < 3; ++i)
        #pragma unroll
        for (int k = 0; k < 4; ++k)
            zb1[i][k] = cvtW(z1 + ((size_t)(m0 + lr) * 3 + i) * 128 + k * 32 + lg * 8);

    // ---- fused proj + products per rank-tile mt ----------------------------
    // proj C-layout (swapped operands): lane holds token t=lr,
    // ranks r = mt*16 + lg*4 + j in acc[j].
    const f32x4 zero = {0.f, 0.f, 0.f, 0.f};
    bf16x8 pa0[4], pa1[3][4];                 // out-GEMM A-frags, built in-lane
    #pragma unroll
    for (int mt = 0; mt < 4; ++mt) {
        f32x4 L0 = zero, R0 = zero, L1[3] = {zero, zero, zero}, R1[3] = {zero, zero, zero};
        #pragma unroll
        for (int k = 0; k < 4; ++k) {
            bf16x8 w0 = WS ? wsf[FA_ID(0, mt, k) * 64 + l]
                           : cvtW(W0l + (mt * 16 + lr) * 128 + k * 32 + lg * 8);
            bf16x8 w1 = WS ? wsf[FA_ID(1, mt, k) * 64 + l]
                           : cvtW(W0r + (mt * 16 + lr) * 128 + k * 32 + lg * 8);
            bf16x8 w2 = WS ? wsf[FA_ID(2, mt, k) * 64 + l]
                           : cvtW(W1l + (mt * 16 + lr) * 128 + k * 32 + lg * 8);
            bf16x8 w3 = WS ? wsf[FA_ID(3, mt, k) * 64 + l]
                           : cvtW(W1r + (mt * 16 + lr) * 128 + k * 32 + lg * 8);
            L0 = mm(w0, zb0[k], L0);          // A = W (ranks), B = z (tokens)
            R0 = mm(w1, zb0[k], R0);
            #pragma unroll
            for (int i = 0; i < 3; ++i) {
                L1[i] = mm(w2, zb1[i][k], L1[i]);
                R1[i] = mm(w3, zb1[i][k], R1[i]);
            }
        }
        // biases (rank-indexed -> per-reg vector add)
        L0 += *(const f32x4*)(b0l + mt * 16 + lg * 4);
        R0 += *(const f32x4*)(b0r + mt * 16 + lg * 4);

        // products: all at (r, t) = (same lane, same reg) -> register math
        const f32x4 p00  = L0 * R0;
        const f32x4 p110 = L1[0] * R1[0] + L1[1] * R1[1] + L1[2] * R1[2];
        pa0[mt] = pack8(p00, p110);           // kk-pairs (p00, p110)
        #pragma unroll
        for (int i = 0; i < 3; ++i) {
            const int i1 = (i == 2) ? 0 : i + 1;
            const int i2 = (i == 0) ? 2 : i - 1;
            const f32x4 q011 = L0 * R1[i];
            const f32x4 q101 = L1[i] * R0;
            pa1[i][mt] = pack8(q011, q101);   // kk-pairs (q011, q101)
            const f32x4 q111 = L1[i1] * R1[i2] - L1[i2] * R1[i1];
            // q111 needs cross-lg redistribution -> 2KB/i LDS, swizzled b64
            const int o = lr * 128 + mt * 32 + lg * 8;
            *(uint2*)(smem + i * 2048 + (o ^ ((lr & 7) << 4))) =
                make_uint2(packbf(q111[0], q111[1]), packbf(q111[2], q111[3]));
        }
    }

    // ---- q111 A-frags from LDS (same-wave RAW; compiler inserts lgkmcnt) ---
    bf16x8 pq[3][2];
    #pragma unroll
    for (int i = 0; i < 3; ++i)
        #pragma unroll
        for (int k2 = 0; k2 < 2; ++k2) {
            const int o = lr * 128 + k2 * 64 + lg * 16;
            pq[i][k2] = *(const bf16x8*)(smem + i * 2048 + (o ^ ((lr & 7) << 4)));
        }

    // ---- output GEMMs + store ----------------------------------------------
    #pragma unroll
    for (int n8 = 0; n8 < 8; ++n8) {
        f32x4 o0 = zero, o1[3] = {zero, zero, zero};
        #pragma unroll
        for (int k = 0; k < 4; ++k) {
            bf16x8 b = WS ? wsf[FB0_ID(n8, k) * 64 + l] : gatherB0(W0o, n8, k, lr, lg);
            o0 = mm(pa0[k], b, o0);
        }
        #pragma unroll
        for (int k6 = 0; k6 < 6; ++k6) {
            bf16x8 b = WS ? wsf[FB1_ID(n8, k6) * 64 + l] : gatherB1(W1o, n8, k6, lr, lg);
            #pragma unroll
            for (int i = 0; i < 3; ++i)
                o1[i] = mm(k6 < 4 ? pa1[i][k6] : pq[i][k6 - 4], b, o1[i]);
        }
        const int c = n8 * 16 + lr;
        const float bo = b0o[c];
        #pragma unroll
        for (int j = 0; j < 4; ++j) {
            const size_t t = m0 + lg * 4 + j;
            out0[t * 128 + c] = o0[j] + bo;
            #pragma unroll
            for (int i = 0; i < 3; ++i)
                out1[(t * 3 + i) * 128 + c] = o1[i][j];
        }
    }
}

extern "C" void kernel_launch(void* const* d_in, const int* in_sizes, int n_in,
                              void* d_out, int out_size, void* d_ws, size_t ws_size,
                              hipStream_t stream)
{
    const float* z0  = (const float*)d_in[0];
    const float* z1  = (const float*)d_in[1];
    const float* W0l = (const float*)d_in[2];
    const float* b0l = (const float*)d_in[3];
    const float* W0r = (const float*)d_in[4];
    const float* b0r = (const float*)d_in[5];
    const float* W1l = (const float*)d_in[6];
    const float* W1r = (const float*)d_in[7];
    const float* W0o = (const float*)d_in[8];
    const float* b0o = (const float*)d_in[9];
    const float* W1o = (const float*)d_in[10];

    const int tokens = in_sizes[0] / 128;        // 65536
    float* out0 = (float*)d_out;
    float* out1 = out0 + (size_t)tokens * 128;
    bf16x8* wsf = (bf16x8*)d_ws;

    if (ws_size >= (size_t)WS_NEED) {
        hipLaunchKernelGGL(etp_setup, dim3((NFRAG * 64 + 255) / 256), dim3(256), 0, stream,
                           W0l, W0r, W1l, W1r, W0o, W1o, wsf);
        hipLaunchKernelGGL((etp_main<true>), dim3(tokens / 16), dim3(64), 0, stream,
                           z0, z1, W0l, b0l, W0r, b0r, W1l, W1r, W0o, b0o, W1o,
                           wsf, out0, out1);
    } else {
        hipLaunchKernelGGL((etp_main<false>), dim3(tokens / 16), dim3(64), 0, stream,
                           z0, z1, W0l, b0l, W0r, b0r, W1l, W1r, W0o, b0o, W1o,
                           wsf, out0, out1);
    }
}